// Round 5
// baseline (485.407 us; speedup 1.0000x reference)
//
#include <hip/hip_runtime.h>
#include <hip/hip_bf16.h>

// ---------------- problem dims ----------------
#define NT  512      // tokens
#define NH  2048     // hidden
#define NE  8        // experts
#define NI  1408     // expert intermediate
#define NIS 5632     // shared intermediate

typedef __bf16 bf16x8 __attribute__((ext_vector_type(8)));
typedef float  f32x4  __attribute__((ext_vector_type(4)));

// ---------------- workspace layout (bytes) ----------------
static constexpr size_t WS_XBF  = 0;                                // 512*2048 bf16
static constexpr size_t WS_SEL  = WS_XBF + (size_t)NT*NH*2;         // 1024 int
static constexpr size_t WS_WTS  = WS_SEL + 1024*4;                  // 1024 float
static constexpr size_t WS_CNT  = WS_WTS + 1024*4;                  // 8 int
static constexpr size_t WS_OFFE = WS_CNT + 32;                      // 8 int
static constexpr size_t WS_TOK  = WS_OFFE + 32;                     // 1024 int
static constexpr size_t WS_PWT  = WS_TOK + 1024*4;                  // 1024 float
static constexpr size_t WS_SLOT = WS_PWT + 1024*4;                  // 1024 int
static constexpr size_t WS_G    = WS_SLOT + 1024*4;                 // 1024*1408 f32
static constexpr size_t WS_U    = WS_G + (size_t)1024*NI*4;
static constexpr size_t WS_HBF  = WS_U + (size_t)1024*NI*4;         // 1024*1408 bf16
static constexpr size_t WS_PAIR = WS_HBF + (size_t)1024*NI*2;       // 1024*2048 f32
static constexpr size_t WS_SHG  = WS_PAIR + (size_t)1024*NH*4;      // 512*5632 f32 (later: 4x shd partials alias here)
static constexpr size_t WS_SHU  = WS_SHG + (size_t)NT*NIS*4;
static constexpr size_t WS_SHBF = WS_SHU + (size_t)NT*NIS*4;        // 512*5632 bf16

// raw barrier: commit this wave's LDS ops, do NOT drain vmcnt (T4)
#define BAR() { asm volatile("s_waitcnt lgkmcnt(0)" ::: "memory"); __builtin_amdgcn_s_barrier(); }

// ---------------- router ----------------
__global__ void router_kernel(const float* __restrict__ x, const float* __restrict__ gw,
                              float* __restrict__ out_logits,
                              int* __restrict__ sel, float* __restrict__ wts)
{
    int tid = threadIdx.x;
    int t = blockIdx.x * 32 + (tid >> 3);
    int e = tid & 7;
    const float* xr = x + (size_t)t * NH;
    const float* gr = gw + (size_t)e * NH;
    float acc = 0.f;
    for (int k = 0; k < NH; k += 4) {
        float4 xv = *(const float4*)(xr + k);
        float4 gv = *(const float4*)(gr + k);
        acc += xv.x*gv.x + xv.y*gv.y + xv.z*gv.z + xv.w*gv.w;
    }
    out_logits[(size_t)t * NE + e] = acc;

    __shared__ float lg[32][8];
    lg[tid >> 3][e] = acc;
    __syncthreads();
    if (e == 0) {
        int ti = tid >> 3;
        float l[8];
        #pragma unroll
        for (int j = 0; j < 8; ++j) l[j] = lg[ti][j];
        int i1 = 0;
        #pragma unroll
        for (int j = 1; j < 8; ++j) if (l[j] > l[i1]) i1 = j;
        int i2 = -1;
        #pragma unroll
        for (int j = 0; j < 8; ++j) {
            if (j == i1) continue;
            if (i2 < 0 || l[j] > l[i2]) i2 = j;
        }
        float d  = expf(l[i2] - l[i1]);
        float w1 = 1.f / (1.f + d);
        float w2 = 1.f - w1;
        sel[2*t]   = i1;  sel[2*t+1] = i2;
        wts[2*t]   = w1;  wts[2*t+1] = w2;
    }
}

// ---------------- deterministic bucketing ----------------
__global__ void bucket_kernel(const int* __restrict__ sel, const float* __restrict__ wts,
                              int* __restrict__ cnt, int* __restrict__ offe,
                              int* __restrict__ tok, float* __restrict__ pwt,
                              int* __restrict__ slot)
{
    int e = threadIdx.x;
    __shared__ int scnt[8];
    __shared__ int soff[8];
    if (e < 8) {
        int c = 0;
        for (int t = 0; t < NT; ++t) {
            if (sel[2*t]   == e) c++;
            if (sel[2*t+1] == e) c++;
        }
        scnt[e] = c;
        cnt[e] = c;
    }
    __syncthreads();
    if (threadIdx.x == 0) {
        int s = 0;
        for (int j = 0; j < 8; ++j) { soff[j] = s; offe[j] = s; s += scnt[j]; }
    }
    __syncthreads();
    if (e < 8) {
        int p = soff[e];
        for (int t = 0; t < NT; ++t) {
            #pragma unroll
            for (int k = 0; k < 2; ++k) {
                if (sel[2*t+k] == e) {
                    tok[p] = t;
                    pwt[p] = wts[2*t+k];
                    slot[2*t+k] = p;
                    p++;
                }
            }
        }
    }
}

// ---------------- fp32 -> bf16 cast ----------------
__global__ void cast_kernel(const float* __restrict__ src, __bf16* __restrict__ dst, long long n)
{
    long long i = ((long long)blockIdx.x * blockDim.x + threadIdx.x) * 4;
    if (i >= n) return;
    float4 v = *(const float4*)(src + i);
    __bf16 o[4] = { (__bf16)v.x, (__bf16)v.y, (__bf16)v.z, (__bf16)v.w };
    *(uint2*)(dst + i) = *(const uint2*)o;
}

// ---------------- fused silu(g)*u -> bf16 ----------------
__global__ void silu_fused_kernel(const float* __restrict__ g1, const float* __restrict__ u1,
                                  __bf16* __restrict__ h1, long long n1,
                                  const float* __restrict__ g2, const float* __restrict__ u2,
                                  __bf16* __restrict__ h2, long long n2)
{
    long long i = ((long long)blockIdx.x * blockDim.x + threadIdx.x) * 4;
    const float* g; const float* u; __bf16* h; long long idx;
    if (i < n1)            { g = g1; u = u1; h = h1; idx = i; }
    else if (i < n1 + n2)  { g = g2; u = u2; h = h2; idx = i - n1; }
    else return;
    float4 gv = *(const float4*)(g + idx);
    float4 uv = *(const float4*)(u + idx);
    float r0 = gv.x / (1.f + __expf(-gv.x)) * uv.x;
    float r1 = gv.y / (1.f + __expf(-gv.y)) * uv.y;
    float r2 = gv.z / (1.f + __expf(-gv.z)) * uv.z;
    float r3 = gv.w / (1.f + __expf(-gv.w)) * uv.w;
    __bf16 o[4] = { (__bf16)r0, (__bf16)r1, (__bf16)r2, (__bf16)r3 };
    *(uint2*)(h + idx) = *(const uint2*)o;
}

// ================= core 256x128 MFMA GEMM, counted-vmcnt pipeline ==========
// C[base+r, n0..n0+127] = sum_k A[row(r), k] * bf16(B[k, n0..]).
// A bf16 [*, LDA]; B fp32 [*, N] row-major (pre-offset); C fp32 [*, N].
// NK = number of 32-k steps (even).
template<int N, int LDA, int NK, bool GATHER>
__device__ __forceinline__ void gemm_core(char* __restrict__ smem,
    const __bf16* __restrict__ A, const float* __restrict__ B,
    float* __restrict__ C, int rows, int base, const int* __restrict__ tok,
    int m0, int n0)
{
    __bf16 (*As0)[40] = (__bf16(*)[40])(smem);            // 256 x 40
    __bf16 (*Bs0)[40] = (__bf16(*)[40])(smem + 20480);    // 128 x 40
    __bf16 (*As1)[40] = (__bf16(*)[40])(smem + 30720);
    __bf16 (*Bs1)[40] = (__bf16(*)[40])(smem + 51200);

    const int tid  = threadIdx.x;      // 0..511
    const int lane = tid & 63;
    const int wid  = tid >> 6;         // 0..7
    const int wr   = wid >> 1, wc = wid & 1;   // 4 x 2 wave grid, 64x64 each

    // A staging: row = tid>>1 (256 rows), 16-bf16 half = tid&1
    const int ar = tid >> 1;
    const int ah = tid & 1;
    const int arow = m0 + ar;
    const bool avalid = (arow < rows);
    int asrc = 0;
    if (avalid) asrc = GATHER ? tok[base + arow] : (base + arow);
    const __bf16* Ap = A + (size_t)asrc * LDA + ah * 16;

    // B staging: col = tid&127, k-chunk = tid>>7 (8 consecutive k)
    const int bn = tid & 127;
    const int kc = tid >> 7;
    const float* Bp = B + (size_t)(kc * 8) * N + n0 + bn;

    struct Tile { uint4 a0, a1; float b[8]; };
    Tile r0, r1;
    r0.a0 = r0.a1 = r1.a0 = r1.a1 = make_uint4(0,0,0,0);

    f32x4 acc[4][4];
    #pragma unroll
    for (int i = 0; i < 4; ++i)
        #pragma unroll
        for (int j = 0; j < 4; ++j) acc[i][j] = f32x4{0.f,0.f,0.f,0.f};

#define LOADSET(R, T)                                                           \
    {                                                                           \
        if (avalid) {                                                           \
            const uint4* ap = (const uint4*)(Ap + (T) * 32);                    \
            R.a0 = ap[0]; R.a1 = ap[1];                                         \
        }                                                                       \
        const float* bp = Bp + (size_t)(T) * 32 * N;                            \
        _Pragma("unroll")                                                       \
        for (int j = 0; j < 8; ++j) R.b[j] = bp[j * N];                         \
    }

#define STORESET(R, AsX, BsX)                                                   \
    {                                                                           \
        *(uint4*)&AsX[ar][ah*16]     = R.a0;                                    \
        *(uint4*)&AsX[ar][ah*16 + 8] = R.a1;                                    \
        bf16x8 pk;                                                              \
        _Pragma("unroll")                                                       \
        for (int j = 0; j < 8; ++j) pk[j] = (__bf16)R.b[j];                     \
        *(bf16x8*)&BsX[bn][kc*8] = pk;                                          \
    }

#define MFMASET(AsX, BsX)                                                       \
    {                                                                           \
        bf16x8 af[4], bfr[4];                                                   \
        _Pragma("unroll")                                                       \
        for (int m = 0; m < 4; ++m)                                             \
            af[m] = *(const bf16x8*)&AsX[wr*64 + m*16 + (lane & 15)][(lane >> 4) * 8]; \
        _Pragma("unroll")                                                       \
        for (int n = 0; n < 4; ++n)                                             \
            bfr[n] = *(const bf16x8*)&BsX[wc*64 + n*16 + (lane & 15)][(lane >> 4) * 8]; \
        __builtin_amdgcn_s_setprio(1);                                          \
        _Pragma("unroll")                                                       \
        for (int m = 0; m < 4; ++m)                                             \
            _Pragma("unroll")                                                   \
            for (int n = 0; n < 4; ++n)                                         \
                acc[m][n] = __builtin_amdgcn_mfma_f32_16x16x32_bf16(af[m], bfr[n], acc[m][n], 0, 0, 0); \
        __builtin_amdgcn_s_setprio(0);                                          \
    }

    LOADSET(r0, 0);
    if (NK > 1) LOADSET(r1, 1);
    STORESET(r0, As0, Bs0);
    if (NK > 2) LOADSET(r0, 2);
    BAR();

    #pragma unroll 1
    for (int t = 0; t < NK; t += 2) {
        STORESET(r1, As1, Bs1);          // vmcnt counted: waits only r1's loads
        if (t + 3 < NK) LOADSET(r1, t + 3);
        MFMASET(As0, Bs0);
        BAR();                           // LDS committed; global loads stay in flight
        if (t + 2 < NK) STORESET(r0, As0, Bs0);
        if (t + 4 < NK) LOADSET(r0, t + 4);
        MFMASET(As1, Bs1);
        BAR();
    }

#undef LOADSET
#undef STORESET
#undef MFMASET

    // ---- epilogue: per-wave LDS transpose, 4 waves at a time (LDS <= 60KB) --
    const int grow = m0 + wr*64 + lane;
    #pragma unroll 1
    for (int half = 0; half < 2; ++half) {
        if ((wid >> 2) == half) {
            float* ep = (float*)(smem + (wid & 3) * 8704);   // 64 rows x 34 f32
            #pragma unroll
            for (int nh = 0; nh < 2; ++nh) {
                if (nh) __builtin_amdgcn_s_waitcnt(0);
                #pragma unroll
                for (int m = 0; m < 4; ++m)
                    #pragma unroll
                    for (int nn = 0; nn < 2; ++nn)
                        #pragma unroll
                        for (int q = 0; q < 4; ++q)
                            ep[(m*16 + (lane>>4)*4 + q)*34 + nn*16 + (lane & 15)] = acc[m][nh*2+nn][q];
                if (grow < rows) {
                    const float* rp = ep + lane * 34;
                    float* cp = C + (size_t)(base + grow) * N + n0 + wc*64 + nh*32;
                    #pragma unroll
                    for (int j = 0; j < 8; ++j) {
                        float2 x0 = *(const float2*)(rp + 4*j);
                        float2 x1 = *(const float2*)(rp + 4*j + 2);
                        *(float4*)(cp + 4*j) = make_float4(x0.x, x0.y, x1.x, x1.y);
                    }
                }
            }
        }
        BAR();
    }
}

// ---------------- phase 1: expert gate/up + shared gate/up ----------
__launch_bounds__(512, 2)
__global__ void gemm_phase1(const __bf16* __restrict__ xbf,
                            const float* __restrict__ w_gate, const float* __restrict__ w_up,
                            const float* __restrict__ sh_gate, const float* __restrict__ sh_up,
                            float* __restrict__ gbuf, float* __restrict__ ubuf,
                            float* __restrict__ shg, float* __restrict__ shu,
                            const int* __restrict__ cnt, const int* __restrict__ offe,
                            const int* __restrict__ tok)
{
    __shared__ alignas(16) char smem[61440];
    int z = blockIdx.z;
    if (z < 16) {
        if (blockIdx.x >= 11) return;           // NI/128 = 11 n-tiles
        int e = z & 7;
        int rows = cnt[e], base = offe[e];
        int m0 = blockIdx.y * 256; if (m0 >= rows) return;
        const float* B = (z < 8 ? w_gate : w_up) + (size_t)e * NH * NI;
        float* C = (z < 8 ? gbuf : ubuf);
        gemm_core<NI, NH, 64, true>(smem, xbf, B, C, rows, base, tok, m0, blockIdx.x * 128);
    } else {
        // 44 n-tiles x 2 m-tiles, XCD-chunked so pair members land on same XCD
        int l = blockIdx.y * 48 + blockIdx.x;   // 0..95
        int m = (l >> 3) & 1;
        int p = (l & 7) | ((l >> 4) << 3);
        if (p >= 44) return;
        const float* B = (z == 16 ? sh_gate : sh_up);
        float* C = (z == 16 ? shg : shu);
        gemm_core<NIS, NH, 64, false>(smem, xbf, B, C, NT, 0, nullptr, m * 256, p * 128);
    }
}

// ---------------- phase 3: expert down + shared down (split-K x4) ----------
__launch_bounds__(512, 2)
__global__ void gemm_phase3(const __bf16* __restrict__ hbf, const __bf16* __restrict__ shbf,
                            const float* __restrict__ w_down, const float* __restrict__ sh_down,
                            float* __restrict__ pair, float* __restrict__ shp,
                            const int* __restrict__ cnt, const int* __restrict__ offe)
{
    __shared__ alignas(16) char smem[61440];
    int z = blockIdx.z;
    if (z < 8) {
        int rows = cnt[z], base = offe[z];
        int m0 = blockIdx.y * 256; if (m0 >= rows) return;
        gemm_core<NH, NI, 44, false>(smem, hbf, w_down + (size_t)z * NI * NH, pair,
                                     rows, base, nullptr, m0, blockIdx.x * 128);
    } else {
        int q = z - 8;                           // K-quarter 0..3
        int l = blockIdx.y * 16 + blockIdx.x;    // 0..31
        int m = (l >> 3) & 1;
        int p = (l & 7) | ((l >> 4) << 3);       // 0..15
        gemm_core<NH, NIS, 44, false>(smem, shbf + q * 1408,
                                      sh_down + (size_t)q * 1408 * NH,
                                      shp + (size_t)q * NT * NH,
                                      NT, 0, nullptr, m * 256, p * 128);
    }
}

// ---------------- final combine (sums 4 shared-down partials) ----------------
__global__ void combine_kernel(const float* __restrict__ x, const float* __restrict__ shexp_w,
                               const float* __restrict__ shp, const float* __restrict__ pair_out,
                               const int* __restrict__ slot, const float* __restrict__ wts,
                               float* __restrict__ out)
{
    int t = blockIdx.x;
    int tid = threadIdx.x;
    const float* xr = x + (size_t)t * NH;

    float p = 0.f;
    #pragma unroll
    for (int j = 0; j < 8; ++j) {
        int k = tid * 8 + j;
        p += xr[k] * shexp_w[k];
    }
    __shared__ float red[256];
    red[tid] = p;
    __syncthreads();
    for (int s = 128; s > 0; s >>= 1) {
        if (tid < s) red[tid] += red[tid + s];
        __syncthreads();
    }
    float sig = 1.f / (1.f + expf(-red[0]));

    int   s0 = slot[2*t],   s1 = slot[2*t+1];
    float w0 = wts[2*t],    w1 = wts[2*t+1];
    const float* pr0 = pair_out + (size_t)s0 * NH;
    const float* pr1 = pair_out + (size_t)s1 * NH;
    const float* sd  = shp + (size_t)t * NH;
    float* orow = out + (size_t)t * NH;
    const size_t PS = (size_t)NT * NH;
    for (int n = tid; n < NH; n += 256) {
        float sdv = sd[n] + sd[n + PS] + sd[n + 2*PS] + sd[n + 3*PS];
        orow[n] = sdv * sig + w0 * pr0[n] + w1 * pr1[n];
    }
}

// ---------------- launch ----------------
extern "C" void kernel_launch(void* const* d_in, const int* in_sizes, int n_in,
                              void* d_out, int out_size, void* d_ws, size_t ws_size,
                              hipStream_t stream)
{
    const float* x       = (const float*)d_in[0];
    const float* gate_w  = (const float*)d_in[1];
    const float* w_gate  = (const float*)d_in[2];
    const float* w_up    = (const float*)d_in[3];
    const float* w_down  = (const float*)d_in[4];
    const float* sh_gate = (const float*)d_in[5];
    const float* sh_up   = (const float*)d_in[6];
    const float* sh_down = (const float*)d_in[7];
    const float* shexp_g = (const float*)d_in[8];

    float* out        = (float*)d_out;
    float* out_logits = out + (size_t)NT * NH;

    char* ws = (char*)d_ws;
    __bf16* xbf  = (__bf16*)(ws + WS_XBF);
    int*    sel  = (int*)  (ws + WS_SEL);
    float*  wts  = (float*)(ws + WS_WTS);
    int*    cnt  = (int*)  (ws + WS_CNT);
    int*    offe = (int*)  (ws + WS_OFFE);
    int*    tok  = (int*)  (ws + WS_TOK);
    float*  pwt  = (float*)(ws + WS_PWT);
    int*    slot = (int*)  (ws + WS_SLOT);
    float*  gbuf = (float*)(ws + WS_G);
    float*  ubuf = (float*)(ws + WS_U);
    __bf16* hbf  = (__bf16*)(ws + WS_HBF);
    float*  pair = (float*)(ws + WS_PAIR);
    float*  shg  = (float*)(ws + WS_SHG);
    float*  shu  = (float*)(ws + WS_SHU);
    __bf16* shbf = (__bf16*)(ws + WS_SHBF);
    float*  shp  = shg;   // 4 shared-down partials alias dead shg/shu
    (void)pwt; (void)in_sizes; (void)n_in; (void)out_size; (void)ws_size;

    router_kernel<<<dim3(16), dim3(256), 0, stream>>>(x, gate_w, out_logits, sel, wts);
    bucket_kernel<<<dim3(1), dim3(64), 0, stream>>>(sel, wts, cnt, offe, tok, pwt, slot);
    cast_kernel<<<dim3(1024), dim3(256), 0, stream>>>(x, xbf, (long long)NT * NH);

    // phase 1: expert gate(z=0..7), expert up(z=8..15), shared gate(16), shared up(17)
    gemm_phase1<<<dim3(48, 2, 18), dim3(512), 0, stream>>>(
        xbf, w_gate, w_up, sh_gate, sh_up, gbuf, ubuf, shg, shu, cnt, offe, tok);

    // phase 2: fused silu
    silu_fused_kernel<<<dim3(4224), dim3(256), 0, stream>>>(
        gbuf, ubuf, hbf, (long long)1024 * NI,
        shg, shu, shbf, (long long)NT * NIS);

    // phase 3: expert down (z=0..7), shared down split-K x4 (z=8..11)
    gemm_phase3<<<dim3(16, 2, 12), dim3(512), 0, stream>>>(
        hbf, shbf, w_down, sh_down, pair, shp, cnt, offe);

    combine_kernel<<<dim3(NT), dim3(256), 0, stream>>>(
        x, shexp_g, shp, pair, slot, wts, out);
}

// Round 6
// 471.765 us; speedup vs baseline: 1.0289x; 1.0289x over previous
//
#include <hip/hip_runtime.h>
#include <hip/hip_bf16.h>

// ---------------- problem dims ----------------
#define NT  512      // tokens
#define NH  2048     // hidden
#define NE  8        // experts
#define NI  1408     // expert intermediate
#define NIS 5632     // shared intermediate

typedef __bf16 bf16x8 __attribute__((ext_vector_type(8)));
typedef float  f32x4  __attribute__((ext_vector_type(4)));

// ---------------- workspace layout (bytes) ----------------
static constexpr size_t WS_XBF  = 0;                                // 512*2048 bf16
static constexpr size_t WS_SEL  = WS_XBF + (size_t)NT*NH*2;         // 1024 int
static constexpr size_t WS_WTS  = WS_SEL + 1024*4;                  // 1024 float
static constexpr size_t WS_CNT  = WS_WTS + 1024*4;                  // 8 int
static constexpr size_t WS_OFFE = WS_CNT + 32;                      // 8 int
static constexpr size_t WS_TOK  = WS_OFFE + 32;                     // 1024 int
static constexpr size_t WS_PWT  = WS_TOK + 1024*4;                  // 1024 float
static constexpr size_t WS_SLOT = WS_PWT + 1024*4;                  // 1024 int
static constexpr size_t WS_G    = WS_SLOT + 1024*4;                 // 1024*1408 f32
static constexpr size_t WS_U    = WS_G + (size_t)1024*NI*4;
static constexpr size_t WS_HBF  = WS_U + (size_t)1024*NI*4;         // 1024*1408 bf16
static constexpr size_t WS_PAIR = WS_HBF + (size_t)1024*NI*2;       // 1024*2048 f32
static constexpr size_t WS_SHG  = WS_PAIR + (size_t)1024*NH*4;      // 512*5632 f32 (later: 4x shd partials alias here)
static constexpr size_t WS_SHU  = WS_SHG + (size_t)NT*NIS*4;
static constexpr size_t WS_SHBF = WS_SHU + (size_t)NT*NIS*4;        // 512*5632 bf16

// raw barrier: commit this wave's LDS ops, do NOT drain vmcnt (T4)
#define BAR() { asm volatile("s_waitcnt lgkmcnt(0)" ::: "memory"); __builtin_amdgcn_s_barrier(); }

// ---------------- router ----------------
__global__ void router_kernel(const float* __restrict__ x, const float* __restrict__ gw,
                              float* __restrict__ out_logits,
                              int* __restrict__ sel, float* __restrict__ wts)
{
    int tid = threadIdx.x;
    int t = blockIdx.x * 32 + (tid >> 3);
    int e = tid & 7;
    const float* xr = x + (size_t)t * NH;
    const float* gr = gw + (size_t)e * NH;
    float acc = 0.f;
    for (int k = 0; k < NH; k += 4) {
        float4 xv = *(const float4*)(xr + k);
        float4 gv = *(const float4*)(gr + k);
        acc += xv.x*gv.x + xv.y*gv.y + xv.z*gv.z + xv.w*gv.w;
    }
    out_logits[(size_t)t * NE + e] = acc;

    __shared__ float lg[32][8];
    lg[tid >> 3][e] = acc;
    __syncthreads();
    if (e == 0) {
        int ti = tid >> 3;
        float l[8];
        #pragma unroll
        for (int j = 0; j < 8; ++j) l[j] = lg[ti][j];
        int i1 = 0;
        #pragma unroll
        for (int j = 1; j < 8; ++j) if (l[j] > l[i1]) i1 = j;
        int i2 = -1;
        #pragma unroll
        for (int j = 0; j < 8; ++j) {
            if (j == i1) continue;
            if (i2 < 0 || l[j] > l[i2]) i2 = j;
        }
        float d  = expf(l[i2] - l[i1]);
        float w1 = 1.f / (1.f + d);
        float w2 = 1.f - w1;
        sel[2*t]   = i1;  sel[2*t+1] = i2;
        wts[2*t]   = w1;  wts[2*t+1] = w2;
    }
}

// ---------------- deterministic bucketing ----------------
__global__ void bucket_kernel(const int* __restrict__ sel, const float* __restrict__ wts,
                              int* __restrict__ cnt, int* __restrict__ offe,
                              int* __restrict__ tok, float* __restrict__ pwt,
                              int* __restrict__ slot)
{
    int e = threadIdx.x;
    __shared__ int scnt[8];
    __shared__ int soff[8];
    if (e < 8) {
        int c = 0;
        for (int t = 0; t < NT; ++t) {
            if (sel[2*t]   == e) c++;
            if (sel[2*t+1] == e) c++;
        }
        scnt[e] = c;
        cnt[e] = c;
    }
    __syncthreads();
    if (threadIdx.x == 0) {
        int s = 0;
        for (int j = 0; j < 8; ++j) { soff[j] = s; offe[j] = s; s += scnt[j]; }
    }
    __syncthreads();
    if (e < 8) {
        int p = soff[e];
        for (int t = 0; t < NT; ++t) {
            #pragma unroll
            for (int k = 0; k < 2; ++k) {
                if (sel[2*t+k] == e) {
                    tok[p] = t;
                    pwt[p] = wts[2*t+k];
                    slot[2*t+k] = p;
                    p++;
                }
            }
        }
    }
}

// ---------------- fp32 -> bf16 cast ----------------
__global__ void cast_kernel(const float* __restrict__ src, __bf16* __restrict__ dst, long long n)
{
    long long i = ((long long)blockIdx.x * blockDim.x + threadIdx.x) * 4;
    if (i >= n) return;
    float4 v = *(const float4*)(src + i);
    __bf16 o[4] = { (__bf16)v.x, (__bf16)v.y, (__bf16)v.z, (__bf16)v.w };
    *(uint2*)(dst + i) = *(const uint2*)o;
}

// ---------------- fused silu(g)*u -> bf16 ----------------
__global__ void silu_fused_kernel(const float* __restrict__ g1, const float* __restrict__ u1,
                                  __bf16* __restrict__ h1, long long n1,
                                  const float* __restrict__ g2, const float* __restrict__ u2,
                                  __bf16* __restrict__ h2, long long n2)
{
    long long i = ((long long)blockIdx.x * blockDim.x + threadIdx.x) * 4;
    const float* g; const float* u; __bf16* h; long long idx;
    if (i < n1)            { g = g1; u = u1; h = h1; idx = i; }
    else if (i < n1 + n2)  { g = g2; u = u2; h = h2; idx = i - n1; }
    else return;
    float4 gv = *(const float4*)(g + idx);
    float4 uv = *(const float4*)(u + idx);
    float r0 = gv.x / (1.f + __expf(-gv.x)) * uv.x;
    float r1 = gv.y / (1.f + __expf(-gv.y)) * uv.y;
    float r2 = gv.z / (1.f + __expf(-gv.z)) * uv.z;
    float r3 = gv.w / (1.f + __expf(-gv.w)) * uv.w;
    __bf16 o[4] = { (__bf16)r0, (__bf16)r1, (__bf16)r2, (__bf16)r3 };
    *(uint2*)(h + idx) = *(const uint2*)o;
}

// ================= core 256x128 MFMA GEMM, counted-vmcnt pipeline ==========
// Iteration order: MFMA(cur) first (hides latency), THEN the vmcnt-waiting
// STORESET, THEN reissue loads. Each reg tile has a 2-iteration lead.
// C[base+r, n0..n0+127] = sum_k A[row(r), k] * bf16(B[k, n0..]).
// A bf16 [*, LDA]; B fp32 [*, N] row-major (pre-offset); C fp32 [*, N].
// NK = number of 32-k steps (even).
template<int N, int LDA, int NK, bool GATHER>
__device__ __forceinline__ void gemm_core(char* __restrict__ smem,
    const __bf16* __restrict__ A, const float* __restrict__ B,
    float* __restrict__ C, int rows, int base, const int* __restrict__ tok,
    int m0, int n0)
{
    __bf16 (*As0)[40] = (__bf16(*)[40])(smem);            // 256 x 40
    __bf16 (*Bs0)[40] = (__bf16(*)[40])(smem + 20480);    // 128 x 40
    __bf16 (*As1)[40] = (__bf16(*)[40])(smem + 30720);
    __bf16 (*Bs1)[40] = (__bf16(*)[40])(smem + 51200);

    const int tid  = threadIdx.x;      // 0..511
    const int lane = tid & 63;
    const int wid  = tid >> 6;         // 0..7
    const int wr   = wid >> 1, wc = wid & 1;   // 4 x 2 wave grid, 64x64 each

    // A staging: row = tid>>1 (256 rows), 16-bf16 half = tid&1
    const int ar = tid >> 1;
    const int ah = tid & 1;
    const int arow = m0 + ar;
    const bool avalid = (arow < rows);
    int asrc = 0;
    if (avalid) asrc = GATHER ? tok[base + arow] : (base + arow);
    const __bf16* Ap = A + (size_t)asrc * LDA + ah * 16;

    // B staging: col = tid&127, k-chunk = tid>>7 (8 consecutive k)
    const int bn = tid & 127;
    const int kc = tid >> 7;
    const float* Bp = B + (size_t)(kc * 8) * N + n0 + bn;

    struct Tile { uint4 a0, a1; float b[8]; };
    Tile r0, r1;
    r0.a0 = r0.a1 = r1.a0 = r1.a1 = make_uint4(0,0,0,0);

    f32x4 acc[4][4];
    #pragma unroll
    for (int i = 0; i < 4; ++i)
        #pragma unroll
        for (int j = 0; j < 4; ++j) acc[i][j] = f32x4{0.f,0.f,0.f,0.f};

#define LOADSET(R, T)                                                           \
    {                                                                           \
        if (avalid) {                                                           \
            const uint4* ap = (const uint4*)(Ap + (T) * 32);                    \
            R.a0 = ap[0]; R.a1 = ap[1];                                         \
        }                                                                       \
        const float* bp = Bp + (size_t)(T) * 32 * N;                            \
        _Pragma("unroll")                                                       \
        for (int j = 0; j < 8; ++j) R.b[j] = bp[j * N];                         \
    }

#define STORESET(R, AsX, BsX)                                                   \
    {                                                                           \
        *(uint4*)&AsX[ar][ah*16]     = R.a0;                                    \
        *(uint4*)&AsX[ar][ah*16 + 8] = R.a1;                                    \
        bf16x8 pk;                                                              \
        _Pragma("unroll")                                                       \
        for (int j = 0; j < 8; ++j) pk[j] = (__bf16)R.b[j];                     \
        *(bf16x8*)&BsX[bn][kc*8] = pk;                                          \
    }

#define MFMASET(AsX, BsX)                                                       \
    {                                                                           \
        bf16x8 af[4], bfr[4];                                                   \
        _Pragma("unroll")                                                       \
        for (int m = 0; m < 4; ++m)                                             \
            af[m] = *(const bf16x8*)&AsX[wr*64 + m*16 + (lane & 15)][(lane >> 4) * 8]; \
        _Pragma("unroll")                                                       \
        for (int n = 0; n < 4; ++n)                                             \
            bfr[n] = *(const bf16x8*)&BsX[wc*64 + n*16 + (lane & 15)][(lane >> 4) * 8]; \
        __builtin_amdgcn_s_setprio(1);                                          \
        _Pragma("unroll")                                                       \
        for (int m = 0; m < 4; ++m)                                             \
            _Pragma("unroll")                                                   \
            for (int n = 0; n < 4; ++n)                                         \
                acc[m][n] = __builtin_amdgcn_mfma_f32_16x16x32_bf16(af[m], bfr[n], acc[m][n], 0, 0, 0); \
        __builtin_amdgcn_s_setprio(0);                                          \
    }

    // prologue: As0 <- step0, r1 <- step1, r0 <- step2
    LOADSET(r0, 0);
    if (NK > 1) LOADSET(r1, 1);
    STORESET(r0, As0, Bs0);
    if (NK > 2) LOADSET(r0, 2);
    BAR();

    #pragma unroll 1
    for (int t = 0; t < NK; t += 2) {
        MFMASET(As0, Bs0);               // step t   — MFMA FIRST, no vmcnt dependency
        STORESET(r1, As1, Bs1);          // stage step t+1 (vmcnt wait after MFMA cover)
        if (t + 3 < NK) LOADSET(r1, t + 3);
        BAR();
        MFMASET(As1, Bs1);               // step t+1
        if (t + 2 < NK) { STORESET(r0, As0, Bs0); }   // stage step t+2
        if (t + 4 < NK) LOADSET(r0, t + 4);
        BAR();
    }

#undef LOADSET
#undef STORESET
#undef MFMASET

    // ---- epilogue: per-wave LDS transpose, 4 waves at a time (LDS <= 60KB) --
    const int grow = m0 + wr*64 + lane;
    #pragma unroll 1
    for (int half = 0; half < 2; ++half) {
        if ((wid >> 2) == half) {
            float* ep = (float*)(smem + (wid & 3) * 8704);   // 64 rows x 34 f32
            #pragma unroll
            for (int nh = 0; nh < 2; ++nh) {
                if (nh) __builtin_amdgcn_s_waitcnt(0);
                #pragma unroll
                for (int m = 0; m < 4; ++m)
                    #pragma unroll
                    for (int nn = 0; nn < 2; ++nn)
                        #pragma unroll
                        for (int q = 0; q < 4; ++q)
                            ep[(m*16 + (lane>>4)*4 + q)*34 + nn*16 + (lane & 15)] = acc[m][nh*2+nn][q];
                if (grow < rows) {
                    const float* rp = ep + lane * 34;
                    float* cp = C + (size_t)(base + grow) * N + n0 + wc*64 + nh*32;
                    #pragma unroll
                    for (int j = 0; j < 8; ++j) {
                        float2 x0 = *(const float2*)(rp + 4*j);
                        float2 x1 = *(const float2*)(rp + 4*j + 2);
                        *(float4*)(cp + 4*j) = make_float4(x0.x, x0.y, x1.x, x1.y);
                    }
                }
            }
        }
        BAR();
    }
}

// ---------------- phase 1: expert gate/up + shared gate/up ----------
__launch_bounds__(512, 2)
__global__ void gemm_phase1(const __bf16* __restrict__ xbf,
                            const float* __restrict__ w_gate, const float* __restrict__ w_up,
                            const float* __restrict__ sh_gate, const float* __restrict__ sh_up,
                            float* __restrict__ gbuf, float* __restrict__ ubuf,
                            float* __restrict__ shg, float* __restrict__ shu,
                            const int* __restrict__ cnt, const int* __restrict__ offe,
                            const int* __restrict__ tok)
{
    __shared__ alignas(16) char smem[61440];
    int z = blockIdx.z;
    if (z < 16) {
        if (blockIdx.x >= 11) return;           // NI/128 = 11 n-tiles
        int e = z & 7;
        int rows = cnt[e], base = offe[e];
        int m0 = blockIdx.y * 256; if (m0 >= rows) return;
        const float* B = (z < 8 ? w_gate : w_up) + (size_t)e * NH * NI;
        float* C = (z < 8 ? gbuf : ubuf);
        gemm_core<NI, NH, 64, true>(smem, xbf, B, C, rows, base, tok, m0, blockIdx.x * 128);
    } else {
        // 44 n-tiles x 2 m-tiles, XCD-chunked so pair members land on same XCD
        int l = blockIdx.y * 48 + blockIdx.x;   // 0..95
        int m = (l >> 3) & 1;
        int p = (l & 7) | ((l >> 4) << 3);
        if (p >= 44) return;
        const float* B = (z == 16 ? sh_gate : sh_up);
        float* C = (z == 16 ? shg : shu);
        gemm_core<NIS, NH, 64, false>(smem, xbf, B, C, NT, 0, nullptr, m * 256, p * 128);
    }
}

// ---------------- phase 3: expert down + shared down (split-K x4) ----------
__launch_bounds__(512, 2)
__global__ void gemm_phase3(const __bf16* __restrict__ hbf, const __bf16* __restrict__ shbf,
                            const float* __restrict__ w_down, const float* __restrict__ sh_down,
                            float* __restrict__ pair, float* __restrict__ shp,
                            const int* __restrict__ cnt, const int* __restrict__ offe)
{
    __shared__ alignas(16) char smem[61440];
    int z = blockIdx.z;
    if (z < 8) {
        int rows = cnt[z], base = offe[z];
        int m0 = blockIdx.y * 256; if (m0 >= rows) return;
        gemm_core<NH, NI, 44, false>(smem, hbf, w_down + (size_t)z * NI * NH, pair,
                                     rows, base, nullptr, m0, blockIdx.x * 128);
    } else {
        int q = z - 8;                           // K-quarter 0..3
        int l = blockIdx.y * 16 + blockIdx.x;    // 0..31
        int m = (l >> 3) & 1;
        int p = (l & 7) | ((l >> 4) << 3);       // 0..15
        gemm_core<NH, NIS, 44, false>(smem, shbf + q * 1408,
                                      sh_down + (size_t)q * 1408 * NH,
                                      shp + (size_t)q * NT * NH,
                                      NT, 0, nullptr, m * 256, p * 128);
    }
}

// ---------------- final combine (sums 4 shared-down partials) ----------------
__global__ void combine_kernel(const float* __restrict__ x, const float* __restrict__ shexp_w,
                               const float* __restrict__ shp, const float* __restrict__ pair_out,
                               const int* __restrict__ slot, const float* __restrict__ wts,
                               float* __restrict__ out)
{
    int t = blockIdx.x;
    int tid = threadIdx.x;
    const float* xr = x + (size_t)t * NH;

    float p = 0.f;
    #pragma unroll
    for (int j = 0; j < 8; ++j) {
        int k = tid * 8 + j;
        p += xr[k] * shexp_w[k];
    }
    __shared__ float red[256];
    red[tid] = p;
    __syncthreads();
    for (int s = 128; s > 0; s >>= 1) {
        if (tid < s) red[tid] += red[tid + s];
        __syncthreads();
    }
    float sig = 1.f / (1.f + expf(-red[0]));

    int   s0 = slot[2*t],   s1 = slot[2*t+1];
    float w0 = wts[2*t],    w1 = wts[2*t+1];
    const float* pr0 = pair_out + (size_t)s0 * NH;
    const float* pr1 = pair_out + (size_t)s1 * NH;
    const float* sd  = shp + (size_t)t * NH;
    float* orow = out + (size_t)t * NH;
    const size_t PS = (size_t)NT * NH;
    for (int n = tid; n < NH; n += 256) {
        float sdv = sd[n] + sd[n + PS] + sd[n + 2*PS] + sd[n + 3*PS];
        orow[n] = sdv * sig + w0 * pr0[n] + w1 * pr1[n];
    }
}

// ---------------- launch ----------------
extern "C" void kernel_launch(void* const* d_in, const int* in_sizes, int n_in,
                              void* d_out, int out_size, void* d_ws, size_t ws_size,
                              hipStream_t stream)
{
    const float* x       = (const float*)d_in[0];
    const float* gate_w  = (const float*)d_in[1];
    const float* w_gate  = (const float*)d_in[2];
    const float* w_up    = (const float*)d_in[3];
    const float* w_down  = (const float*)d_in[4];
    const float* sh_gate = (const float*)d_in[5];
    const float* sh_up   = (const float*)d_in[6];
    const float* sh_down = (const float*)d_in[7];
    const float* shexp_g = (const float*)d_in[8];

    float* out        = (float*)d_out;
    float* out_logits = out + (size_t)NT * NH;

    char* ws = (char*)d_ws;
    __bf16* xbf  = (__bf16*)(ws + WS_XBF);
    int*    sel  = (int*)  (ws + WS_SEL);
    float*  wts  = (float*)(ws + WS_WTS);
    int*    cnt  = (int*)  (ws + WS_CNT);
    int*    offe = (int*)  (ws + WS_OFFE);
    int*    tok  = (int*)  (ws + WS_TOK);
    float*  pwt  = (float*)(ws + WS_PWT);
    int*    slot = (int*)  (ws + WS_SLOT);
    float*  gbuf = (float*)(ws + WS_G);
    float*  ubuf = (float*)(ws + WS_U);
    __bf16* hbf  = (__bf16*)(ws + WS_HBF);
    float*  pair = (float*)(ws + WS_PAIR);
    float*  shg  = (float*)(ws + WS_SHG);
    float*  shu  = (float*)(ws + WS_SHU);
    __bf16* shbf = (__bf16*)(ws + WS_SHBF);
    float*  shp  = shg;   // 4 shared-down partials alias dead shg/shu
    (void)pwt; (void)in_sizes; (void)n_in; (void)out_size; (void)ws_size;

    router_kernel<<<dim3(16), dim3(256), 0, stream>>>(x, gate_w, out_logits, sel, wts);
    bucket_kernel<<<dim3(1), dim3(64), 0, stream>>>(sel, wts, cnt, offe, tok, pwt, slot);
    cast_kernel<<<dim3(1024), dim3(256), 0, stream>>>(x, xbf, (long long)NT * NH);

    // phase 1: expert gate(z=0..7), expert up(z=8..15), shared gate(16), shared up(17)
    gemm_phase1<<<dim3(48, 2, 18), dim3(512), 0, stream>>>(
        xbf, w_gate, w_up, sh_gate, sh_up, gbuf, ubuf, shg, shu, cnt, offe, tok);

    // phase 2: fused silu
    silu_fused_kernel<<<dim3(4224), dim3(256), 0, stream>>>(
        gbuf, ubuf, hbf, (long long)1024 * NI,
        shg, shu, shbf, (long long)NT * NIS);

    // phase 3: expert down (z=0..7), shared down split-K x4 (z=8..11)
    gemm_phase3<<<dim3(16, 2, 12), dim3(512), 0, stream>>>(
        hbf, shbf, w_down, sh_down, pair, shp, cnt, offe);

    combine_kernel<<<dim3(NT), dim3(256), 0, stream>>>(
        x, shexp_g, shp, pair, slot, wts, out);
}